// Round 14
// baseline (397.932 us; speedup 1.0000x reference)
//
#include <hip/hip_runtime.h>
#include <cstdio>
#include <cstddef>

#define DH 128

typedef _Float16 f16;
typedef __attribute__((ext_vector_type(8))) _Float16 f16x8;
typedef __attribute__((ext_vector_type(4))) _Float16 f16x4;
typedef __attribute__((ext_vector_type(2))) _Float16 f16x2;
typedef __attribute__((ext_vector_type(4))) float    f32x4;
typedef unsigned int u32;

// ---------------------------------------------------------------------------
// GEMM body: C[M][OUT] = A[M][128] @ B[OUT][128]^T via mfma_f32_16x16x32_f16,
// swapped operands (lane holds 4 consecutive channels at row m). NT row-tiles
// per wave. A/B may be f32 (converted in-register) or f16.
// ---------------------------------------------------------------------------
template<int OUT, int NT, bool AF32, bool BF32, bool WF32, bool WF16, bool FUSES>
__device__ __forceinline__ void gemm_body(int bx, int tid,
                                          const void* __restrict__ Avp,
                                          const void* __restrict__ Bvp,
                                          float* __restrict__ Cf,
                                          f16* __restrict__ Ch,
                                          const float* __restrict__ wg,
                                          float* __restrict__ s,
                                          int M)
{
    const int lane = tid & 63;
    const int row0 = bx * (NT * 64) + (tid >> 6) * (NT * 16);
    const int r = lane & 15, kg = lane >> 4;

    int  mrow[NT];
    bool ok[NT];
    f16x8 a[NT][4];
#pragma unroll
    for (int t = 0; t < NT; ++t) {
        mrow[t] = row0 + t * 16 + r;
        ok[t]   = (mrow[t] < M);
        int ar  = ok[t] ? mrow[t] : M - 1;
        if constexpr (AF32) {
            const float* Af = (const float*)Avp + (size_t)ar * 128 + kg * 8;
#pragma unroll
            for (int q = 0; q < 4; ++q) {
                float4 f0 = *(const float4*)(Af + q * 32);
                float4 f1 = *(const float4*)(Af + q * 32 + 4);
                f16x8 fr = {(f16)f0.x, (f16)f0.y, (f16)f0.z, (f16)f0.w,
                            (f16)f1.x, (f16)f1.y, (f16)f1.z, (f16)f1.w};
                a[t][q] = fr;
            }
        } else {
            const f16x8* Ap = (const f16x8*)((const f16*)Avp + (size_t)ar * 128 + kg * 8);
            a[t][0] = Ap[0]; a[t][1] = Ap[4]; a[t][2] = Ap[8]; a[t][3] = Ap[12];
        }
    }

    float sp0[NT], sp1[NT];
    if constexpr (FUSES) {
#pragma unroll
        for (int t = 0; t < NT; ++t) { sp0[t] = 0.f; sp1[t] = 0.f; }
    }

    for (int ct = 0; ct < OUT / 16; ++ct) {
        f16x8 b0, b1, b2, b3;
        if constexpr (BF32) {
            const float* Bf = (const float*)Bvp + (size_t)(ct * 16 + r) * 128 + kg * 8;
            f16x8 bq[4];
#pragma unroll
            for (int q = 0; q < 4; ++q) {
                float4 f0 = *(const float4*)(Bf + q * 32);
                float4 f1 = *(const float4*)(Bf + q * 32 + 4);
                f16x8 fr = {(f16)f0.x, (f16)f0.y, (f16)f0.z, (f16)f0.w,
                            (f16)f1.x, (f16)f1.y, (f16)f1.z, (f16)f1.w};
                bq[q] = fr;
            }
            b0 = bq[0]; b1 = bq[1]; b2 = bq[2]; b3 = bq[3];
        } else {
            const f16x8* Bp = (const f16x8*)((const f16*)Bvp +
                                             (size_t)(ct * 16 + r) * 128 + kg * 8);
            b0 = Bp[0]; b1 = Bp[4]; b2 = Bp[8]; b3 = Bp[12];
        }
        const int o0 = ct * 16 + kg * 4;
        float w0, w1, w2, w3, u0, u1, u2, u3;
        if constexpr (FUSES) {
            w0 = wg[o0]; w1 = wg[o0+1]; w2 = wg[o0+2]; w3 = wg[o0+3];
            u0 = wg[128+o0]; u1 = wg[128+o0+1]; u2 = wg[128+o0+2]; u3 = wg[128+o0+3];
        }
#pragma unroll
        for (int t = 0; t < NT; ++t) {
            f32x4 acc = {0.f, 0.f, 0.f, 0.f};
            acc = __builtin_amdgcn_mfma_f32_16x16x32_f16(b0, a[t][0], acc, 0, 0, 0);
            acc = __builtin_amdgcn_mfma_f32_16x16x32_f16(b1, a[t][1], acc, 0, 0, 0);
            acc = __builtin_amdgcn_mfma_f32_16x16x32_f16(b2, a[t][2], acc, 0, 0, 0);
            acc = __builtin_amdgcn_mfma_f32_16x16x32_f16(b3, a[t][3], acc, 0, 0, 0);
            if (ok[t]) {
                if constexpr (WF32)
                    *(float4*)(Cf + (size_t)mrow[t] * OUT + o0) =
                        make_float4(acc[0], acc[1], acc[2], acc[3]);
                if constexpr (WF16) {
                    f16x4 hv = {(f16)acc[0], (f16)acc[1], (f16)acc[2], (f16)acc[3]};
                    *(f16x4*)(Ch + (size_t)mrow[t] * OUT + o0) = hv;
                }
            }
            if constexpr (FUSES) {
                sp0[t] += acc[0]*w0 + acc[1]*w1 + acc[2]*w2 + acc[3]*w3;
                sp1[t] += acc[0]*u0 + acc[1]*u1 + acc[2]*u2 + acc[3]*u3;
            }
        }
    }
    if constexpr (FUSES) {
#pragma unroll
        for (int t = 0; t < NT; ++t) {
            float p0 = sp0[t], p1 = sp1[t];
            p0 += __shfl_xor(p0, 16); p0 += __shfl_xor(p0, 32);
            p1 += __shfl_xor(p1, 16); p1 += __shfl_xor(p1, 32);
            if (kg == 0 && ok[t])
                *(float2*)(s + 2 * mrow[t]) = make_float2(p0, p1);
        }
    }
}

// ---------------------------------------------------------------------------
// megaA: blocks [0,CNT_B) degree-count; [CNT_B,CNT_B+128) Bg16 build;
// rest: init GEMM h16 = f16(x @ Ws^T) with fused s (A,B read as f32).
// ---------------------------------------------------------------------------
#define CNT_B 512
__global__ __launch_bounds__(256) void megaA(const float* __restrict__ x,
                                             const float* __restrict__ Ws,
                                             const float* __restrict__ Wpc,
                                             const float* __restrict__ Wedge,
                                             f16* __restrict__ Bg16,
                                             const int* __restrict__ idx,
                                             int* __restrict__ cnt, int twoE,
                                             const float* __restrict__ wg,
                                             float* __restrict__ s,
                                             f16* __restrict__ h16, int M)
{
    const int b = blockIdx.x;
    if (b < CNT_B) {
        const int stride = CNT_B * 256;
        for (int i = b * 256 + threadIdx.x; i < twoE; i += stride)
            atomicAdd(cnt + idx[i], 1);
    } else if (b < CNT_B + 128) {
        int ob = (b - CNT_B) * 2 + (threadIdx.x >> 7);   // output row 0..255
        int k  = threadIdx.x & 127;
        int orow = ob & 127;
        int col  = (ob < 128) ? k : (128 + k);
        float acc = 0.f;
        for (int m = 0; m < 128; ++m)
            acc += Wpc[orow * 128 + m] * Wedge[m * 256 + col];
        Bg16[ob * 128 + k] = (f16)acc;
    } else {
        gemm_body<128, 2, true, true, false, true, true>(b - CNT_B - 128, threadIdx.x,
                                                         x, Ws, nullptr, h16, wg, s, M);
    }
}

// ---------------------------------------------------------------------------
// megaB: blocks [0,FILL_B) XCD-bucketed CSR fill; rest: step GEMM g16 = h16@Bg^T
// ---------------------------------------------------------------------------
#define FILL_B 1280
__global__ __launch_bounds__(256) void megaB(const int* __restrict__ idx,
                                             int* __restrict__ cursor,
                                             int* __restrict__ adjp,
                                             int E, int Nn,
                                             const f16* __restrict__ h16,
                                             const f16* __restrict__ Bg16,
                                             f16* __restrict__ g16, int M)
{
    const int b = blockIdx.x;
    if (b < FILL_B) {
        const int xcd  = b & 7;
        const int gblk = b >> 3;
        const int ngrp = FILL_B >> 3;
        const int twoE = 2 * E;
        const int lo = xcd * Nn, hi = lo + Nn;
        for (int i = gblk * blockDim.x + threadIdx.x; i < twoE; i += ngrp * blockDim.x) {
            int node = idx[i];
            int n8 = node << 3;
            if (n8 < lo || n8 >= hi) continue;
            int side  = (i >= E);
            int e     = side ? i - E : i;
            int other = side ? idx[e] : idx[E + e];
            int pos = atomicAdd(cursor + node, 1);
            adjp[pos] = other | (side << 31);
        }
    } else {
        gemm_body<256, 4, false, false, false, true, false>(b - FILL_B, threadIdx.x,
                                                            h16, Bg16, nullptr, g16,
                                                            nullptr, nullptr, M);
    }
}

// ---------------------------------------------------------------------------
// standalone step GEMM (steps 1,2)
// ---------------------------------------------------------------------------
__global__ __launch_bounds__(256) void gemm256(const f16* __restrict__ A16,
                                               const f16* __restrict__ B16,
                                               f16* __restrict__ Ch, int M)
{
    gemm_body<256, 4, false, false, false, true, false>(blockIdx.x, threadIdx.x,
                                                        A16, B16, nullptr, Ch,
                                                        nullptr, nullptr, M);
}

// ===========================================================================
// CSR scans
// ===========================================================================
#define SCAN_B 256
__global__ __launch_bounds__(SCAN_B) void scan1(const int* __restrict__ cnt,
                                                int* __restrict__ bsum, int Nn)
{
    __shared__ int sm[SCAN_B];
    int i = blockIdx.x * SCAN_B + threadIdx.x;
    sm[threadIdx.x] = (i < Nn) ? cnt[i] : 0;
    __syncthreads();
    for (int off = SCAN_B / 2; off > 0; off >>= 1) {
        if (threadIdx.x < off) sm[threadIdx.x] += sm[threadIdx.x + off];
        __syncthreads();
    }
    if (threadIdx.x == 0) bsum[blockIdx.x] = sm[0];
}

// scan3b: folds the old scan2 (block-prefix of bsum computed per block)
__global__ __launch_bounds__(SCAN_B) void scan3b(const int* __restrict__ cnt,
                                                 const int* __restrict__ bsum,
                                                 int* __restrict__ base,
                                                 int* __restrict__ cursor, int Nn)
{
    __shared__ int sm[SCAN_B];
    __shared__ int spre;
    // prefix over bsum[0 .. blockIdx.x)
    int acc = 0;
    for (int t = threadIdx.x; t < blockIdx.x; t += SCAN_B) acc += bsum[t];
    sm[threadIdx.x] = acc;
    __syncthreads();
    for (int off = SCAN_B / 2; off > 0; off >>= 1) {
        if (threadIdx.x < off) sm[threadIdx.x] += sm[threadIdx.x + off];
        __syncthreads();
    }
    if (threadIdx.x == 0) spre = sm[0];
    __syncthreads();
    const int bpre = spre;
    __syncthreads();
    // local inclusive scan of cnt
    int i = blockIdx.x * SCAN_B + threadIdx.x;
    int v = (i < Nn) ? cnt[i] : 0;
    sm[threadIdx.x] = v;
    __syncthreads();
    for (int off = 1; off < SCAN_B; off <<= 1) {
        int u = (threadIdx.x >= off) ? sm[threadIdx.x - off] : 0;
        __syncthreads();
        sm[threadIdx.x] += u;
        __syncthreads();
    }
    if (i < Nn) {
        int b = bpre + sm[threadIdx.x] - v;
        base[i] = b;
        cursor[i] = b;
        if (i == Nn - 1) base[Nn] = b + v;
    }
}

// ===========================================================================
// per-step fused kernel: FOUR nodes per wave (16-lane groups, 16B/lane).
// h-state lives in f16 (h16); LAST step writes f32 d_out instead.
// ===========================================================================
template<bool LAST>
__global__ __launch_bounds__(256) void agg8(const f16* __restrict__ g16,
                                            const int* __restrict__ adjp,
                                            const int* __restrict__ base,
                                            const float* __restrict__ sIn,
                                            float* __restrict__ sOut,
                                            float* __restrict__ hOut,
                                            f16* __restrict__ h16,
                                            const float* __restrict__ wg,
                                            const float* __restrict__ gbp,
                                            const float* __restrict__ Tp,
                                            float stepf, int Nn, int twoE)
{
    const int lane = threadIdx.x & 63;
    const int grp  = lane >> 4;
    const int gl   = lane & 15;
    const int wvid = (blockIdx.x * blockDim.x + threadIdx.x) >> 6;
    int n = wvid * 4 + grp;
    const bool nOK = (n < Nn);
    if (n >= Nn) n = Nn - 1;
    const float gb = gbp[0];
    const float w  = 1.f / (1.f + expf(-(Tp[0] - stepf)));
    const int b0 = base[n], b1 = base[n + 1];
    const int deg = b1 - b0;
    const float s1n = sIn[2 * n], s2n = sIn[2 * n + 1];
    const int d0 = gl << 3;

    f16x8 o1 = *(const f16x8*)(g16 + (size_t)n * 256 + d0);
    f16x8 o2 = *(const f16x8*)(g16 + (size_t)n * 256 + 128 + d0);
    f16x8 hv16 = *(const f16x8*)(h16 + (size_t)n * DH + d0);

    f16x2 acc0 = {(f16)0.f, (f16)0.f};
    f16x2 acc1 = {(f16)0.f, (f16)0.f};
    f16x2 acc2 = {(f16)0.f, (f16)0.f};
    f16x2 acc3 = {(f16)0.f, (f16)0.f};
    float aPl = 0.f, aCl = 0.f;

    union V8 { f16x8 v; f16x2 h2[4]; };
    union AU { u32 w; f16x2 h; unsigned short us[2]; };

    int t = 0;
    while (__any(t * 16 < deg)) {
        const int done = t * 16;
        int m = deg - done; m = (m < 0) ? 0 : ((m > 16) ? 16 : m);
        int midx = b0 + done + ((gl < m) ? gl : ((m > 0) ? m - 1 : 0));
        midx = (midx < twoE - 1) ? midx : (twoE - 1);
        midx = (midx > 0) ? midx : 0;
        int meta  = adjp[midx];
        int other = meta & 0x7FFFFFFF;
        int side  = ((unsigned)meta) >> 31;
        int eoff  = (other << 8) | ((side ^ 1) << 7);
        float sv  = sIn[2 * other + (side ^ 1)];
        float aE  = 1.f / (1.f + expf(-((side ? s2n : s1n) + sv + gb)));
        if (gl >= m) aE = 0.f;
        aPl += side ? 0.f : aE;
        aCl += side ? aE : 0.f;

        AU apk;
        apk.h[0] = (f16)aE;
        apk.us[1] = apk.us[0];

        const int sb = grp << 4;
        for (int j = 0; j < m; j += 8) {
            V8 gv[8]; u32 ap[8];
#pragma unroll
            for (int u = 0; u < 8; ++u) {
                int es = j + u; es = (es < 15) ? es : 15;
                int eo = __shfl(eoff, sb | es);
                ap[u]  = (u32)__shfl((int)apk.w, sb | es);
                gv[u].v = *(const f16x8*)(g16 + (size_t)(unsigned)eo + d0);
            }
#pragma unroll
            for (int u = 0; u < 8; ++u) {
                AU aa; aa.w = ap[u];
                acc0 += aa.h * gv[u].h2[0];
                acc1 += aa.h * gv[u].h2[1];
                acc2 += aa.h * gv[u].h2[2];
                acc3 += aa.h * gv[u].h2[3];
            }
        }
        ++t;
    }

    float a8[8];
    a8[0] = (float)acc0[0]; a8[1] = (float)acc0[1];
    a8[2] = (float)acc1[0]; a8[3] = (float)acc1[1];
    a8[4] = (float)acc2[0]; a8[5] = (float)acc2[1];
    a8[6] = (float)acc3[0]; a8[7] = (float)acc3[1];

    float aP = aPl, aC = aCl;
#pragma unroll
    for (int off = 8; off > 0; off >>= 1) {
        aP += __shfl_xor(aP, off);
        aC += __shfl_xor(aC, off);
    }
#pragma unroll
    for (int i = 0; i < 8; ++i)
        a8[i] += aP * (float)o1[i] + aC * (float)o2[i];

    float hf[8];
#pragma unroll
    for (int i = 0; i < 8; ++i) {
        hf[i] = (float)hv16[i];
        hf[i] += w * fmaxf(a8[i] + hf[i], 0.f);
    }

    float p0 = 0.f, p1 = 0.f;
    if (nOK) {
        if constexpr (LAST) {
            *(float4*)(hOut + (size_t)n * DH + d0) =
                make_float4(hf[0], hf[1], hf[2], hf[3]);
            *(float4*)(hOut + (size_t)n * DH + d0 + 4) =
                make_float4(hf[4], hf[5], hf[6], hf[7]);
        } else {
            f16x8 h2 = {(f16)hf[0], (f16)hf[1], (f16)hf[2], (f16)hf[3],
                        (f16)hf[4], (f16)hf[5], (f16)hf[6], (f16)hf[7]};
            *(f16x8*)(h16 + (size_t)n * DH + d0) = h2;
        }
    }
    if constexpr (!LAST) {
        float4 w0a = *(const float4*)(wg + d0);
        float4 w0b = *(const float4*)(wg + d0 + 4);
        float4 w1a = *(const float4*)(wg + 128 + d0);
        float4 w1b = *(const float4*)(wg + 128 + d0 + 4);
        p0 = hf[0]*w0a.x + hf[1]*w0a.y + hf[2]*w0a.z + hf[3]*w0a.w
           + hf[4]*w0b.x + hf[5]*w0b.y + hf[6]*w0b.z + hf[7]*w0b.w;
        p1 = hf[0]*w1a.x + hf[1]*w1a.y + hf[2]*w1a.z + hf[3]*w1a.w
           + hf[4]*w1b.x + hf[5]*w1b.y + hf[6]*w1b.z + hf[7]*w1b.w;
#pragma unroll
        for (int off = 8; off > 0; off >>= 1) {
            p0 += __shfl_xor(p0, off);
            p1 += __shfl_xor(p1, off);
        }
        if (gl == 0 && nOK) *(float2*)(sOut + 2 * n) = make_float2(p0, p1);
    }
}

// ---------------------------------------------------------------------------
static inline size_t alignUp(size_t x) { return (x + 255) & ~(size_t)255; }

extern "C" void kernel_launch(void* const* d_in, const int* in_sizes, int n_in,
                              void* d_out, int out_size, void* d_ws, size_t ws_size,
                              hipStream_t stream)
{
    const float* x     = (const float*)d_in[0];
    const int*   idx   = (const int*)d_in[1];
    const float* Ws    = (const float*)d_in[2];
    const float* Wpc   = (const float*)d_in[3];
    const float* Wedge = (const float*)d_in[4];
    const float* Wg    = (const float*)d_in[5];
    const float* Wgb   = (const float*)d_in[6];
    const float* Tp    = (const float*)d_in[7];
    const int Nn = in_sizes[0] / DH;     // 100000
    const int E  = in_sizes[1] / 2;      // 500000
    float* h = (float*)d_out;

    const int nb = (Nn + SCAN_B - 1) / SCAN_B;

    // workspace carve-up
    size_t off = 0;
    char* wsb = (char*)d_ws;
    f16*   g16    = (f16*)  (wsb + off); off = alignUp(off + (size_t)Nn * 256 * 2);
    f16*   h16    = (f16*)  (wsb + off); off = alignUp(off + (size_t)Nn * DH * 2);
    f16*   Bg16   = (f16*)  (wsb + off); off = alignUp(off + 256 * 128 * 2);
    float* sA     = (float*)(wsb + off); off = alignUp(off + (size_t)Nn * 2 * 4);
    float* sB     = (float*)(wsb + off); off = alignUp(off + (size_t)Nn * 2 * 4);
    int*   cnt    = (int*)  (wsb + off); off = alignUp(off + (size_t)Nn * 4);
    int*   base   = (int*)  (wsb + off); off = alignUp(off + (size_t)(Nn + 1) * 4);
    int*   cursor = (int*)  (wsb + off); off = alignUp(off + (size_t)Nn * 4);
    int*   bsum   = (int*)  (wsb + off); off = alignUp(off + (size_t)(nb + 1) * 4);
    int*   adjp   = (int*)  (wsb + off); off = alignUp(off + (size_t)(2 * E + 64) * 4);
    if (off > ws_size) {
        fprintf(stderr, "kernel_launch: ws too small (%zu < %zu)\n", ws_size, off);
        return;
    }

    const int gemmInitBlocks = (Nn + 127) / 128;   // NT=2
    const int gemmStepBlocks = (Nn + 255) / 256;   // NT=4

    // ---- megaA: degree count + Bg16 + init GEMM (h16, fused s) ----
    hipMemsetAsync(cnt, 0, (size_t)Nn * 4, stream);
    megaA<<<dim3(CNT_B + 128 + gemmInitBlocks), dim3(256), 0, stream>>>(
        x, Ws, Wpc, Wedge, Bg16, idx, cnt, 2 * E, Wg, sA, h16, Nn);

    // ---- scans ----
    scan1<<<dim3(nb), dim3(SCAN_B), 0, stream>>>(cnt, bsum, Nn);
    scan3b<<<dim3(nb), dim3(SCAN_B), 0, stream>>>(cnt, bsum, base, cursor, Nn);

    // ---- megaB: CSR fill + step-0 GEMM ----
    megaB<<<dim3(FILL_B + gemmStepBlocks), dim3(256), 0, stream>>>(
        idx, cursor, adjp, E, Nn, h16, Bg16, g16, Nn);

    // ---- 3 steps ----
    const int aggBlocks = (Nn * 16 + 255) / 256;
    float* sCur = sA; float* sNxt = sB;
    for (int step = 0; step < 3; ++step) {
        if (step > 0)
            gemm256<<<dim3(gemmStepBlocks), dim3(256), 0, stream>>>(h16, Bg16, g16, Nn);
        if (step < 2)
            agg8<false><<<dim3(aggBlocks), dim3(256), 0, stream>>>(g16, adjp, base, sCur,
                                                                   sNxt, h, h16, Wg, Wgb,
                                                                   Tp, (float)step, Nn, 2 * E);
        else
            agg8<true><<<dim3(aggBlocks), dim3(256), 0, stream>>>(g16, adjp, base, sCur,
                                                                  sNxt, h, h16, Wg, Wgb,
                                                                  Tp, (float)step, Nn, 2 * E);
        float* t = sCur; sCur = sNxt; sNxt = t;
    }
}

// Round 15
// 382.384 us; speedup vs baseline: 1.0407x; 1.0407x over previous
//
#include <hip/hip_runtime.h>
#include <cstdio>
#include <cstddef>

#define DH 128

typedef _Float16 f16;
typedef __attribute__((ext_vector_type(8))) _Float16 f16x8;
typedef __attribute__((ext_vector_type(4))) _Float16 f16x4;
typedef __attribute__((ext_vector_type(2))) _Float16 f16x2;
typedef __attribute__((ext_vector_type(4))) float    f32x4;
typedef unsigned int u32;

// ---------------------------------------------------------------------------
// prep2: blocks 0..255 -> Bg16 rows; 256..383 -> Ws16 cast; rest -> degree count
// ---------------------------------------------------------------------------
__global__ __launch_bounds__(128) void prep2(const float* __restrict__ Wpc,
                                             const float* __restrict__ Wedge,
                                             const float* __restrict__ Ws,
                                             f16* __restrict__ Bg16,
                                             f16* __restrict__ Ws16,
                                             const int* __restrict__ idx,
                                             int* __restrict__ cnt, int twoE)
{
    int o = blockIdx.x;
    int k = threadIdx.x;
    if (o < 256) {
        int orow = o & 127;
        int col  = (o < 128) ? k : (128 + k);
        float acc = 0.f;
        for (int m = 0; m < 128; ++m)
            acc += Wpc[orow * 128 + m] * Wedge[m * 256 + col];
        Bg16[o * 128 + k] = (f16)acc;
    } else if (o < 384) {
        int row = o - 256;
        Ws16[row * 128 + k] = (f16)Ws[row * 128 + k];
    } else {
        const int stride = (gridDim.x - 384) * 128;
        for (int i = (o - 384) * 128 + k; i < twoE; i += stride)
            atomicAdd(cnt + idx[i], 1);
    }
}

// ---------------------------------------------------------------------------
// C[M][OUT] = A[M][128] @ B16[OUT][128]^T via mfma_f32_16x16x32_f16, swapped
// operands. NT row-tiles per wave. A is f16 (AF32=false) or f32 (converted).
// ---------------------------------------------------------------------------
template<int OUT, int NT, bool AF32, bool WF32, bool WF16, bool FUSES>
__global__ __launch_bounds__(256) void mfma_gemm_t(const void* __restrict__ Avp,
                                                   const f16* __restrict__ B16,
                                                   float* __restrict__ Cf,
                                                   f16* __restrict__ Ch,
                                                   const float* __restrict__ wg,
                                                   float* __restrict__ s,
                                                   int M)
{
    const int lane = threadIdx.x & 63;
    const int row0 = blockIdx.x * (NT * 64) + (threadIdx.x >> 6) * (NT * 16);
    const int r = lane & 15, kg = lane >> 4;

    int  mrow[NT];
    bool ok[NT];
    f16x8 a[NT][4];
#pragma unroll
    for (int t = 0; t < NT; ++t) {
        mrow[t] = row0 + t * 16 + r;
        ok[t]   = (mrow[t] < M);
        int ar  = ok[t] ? mrow[t] : M - 1;
        if constexpr (AF32) {
            const float* Af = (const float*)Avp + (size_t)ar * 128 + kg * 8;
#pragma unroll
            for (int q = 0; q < 4; ++q) {
                float4 f0 = *(const float4*)(Af + q * 32);
                float4 f1 = *(const float4*)(Af + q * 32 + 4);
                f16x8 fr = {(f16)f0.x, (f16)f0.y, (f16)f0.z, (f16)f0.w,
                            (f16)f1.x, (f16)f1.y, (f16)f1.z, (f16)f1.w};
                a[t][q] = fr;
            }
        } else {
            const f16x8* Ap = (const f16x8*)((const f16*)Avp + (size_t)ar * 128 + kg * 8);
            a[t][0] = Ap[0]; a[t][1] = Ap[4]; a[t][2] = Ap[8]; a[t][3] = Ap[12];
        }
    }

    float sp0[NT], sp1[NT];
    if constexpr (FUSES) {
#pragma unroll
        for (int t = 0; t < NT; ++t) { sp0[t] = 0.f; sp1[t] = 0.f; }
    }

    for (int ct = 0; ct < OUT / 16; ++ct) {
        const f16x8* Bp = (const f16x8*)(B16 + (size_t)(ct * 16 + r) * 128 + kg * 8);
        f16x8 b0 = Bp[0], b1 = Bp[4], b2 = Bp[8], b3 = Bp[12];
        const int o0 = ct * 16 + kg * 4;
        float w0, w1, w2, w3, u0, u1, u2, u3;
        if constexpr (FUSES) {
            w0 = wg[o0]; w1 = wg[o0+1]; w2 = wg[o0+2]; w3 = wg[o0+3];
            u0 = wg[128+o0]; u1 = wg[128+o0+1]; u2 = wg[128+o0+2]; u3 = wg[128+o0+3];
        }
#pragma unroll
        for (int t = 0; t < NT; ++t) {
            f32x4 acc = {0.f, 0.f, 0.f, 0.f};
            acc = __builtin_amdgcn_mfma_f32_16x16x32_f16(b0, a[t][0], acc, 0, 0, 0);
            acc = __builtin_amdgcn_mfma_f32_16x16x32_f16(b1, a[t][1], acc, 0, 0, 0);
            acc = __builtin_amdgcn_mfma_f32_16x16x32_f16(b2, a[t][2], acc, 0, 0, 0);
            acc = __builtin_amdgcn_mfma_f32_16x16x32_f16(b3, a[t][3], acc, 0, 0, 0);
            if (ok[t]) {
                if constexpr (WF32)
                    *(float4*)(Cf + (size_t)mrow[t] * OUT + o0) =
                        make_float4(acc[0], acc[1], acc[2], acc[3]);
                if constexpr (WF16) {
                    f16x4 hv = {(f16)acc[0], (f16)acc[1], (f16)acc[2], (f16)acc[3]};
                    *(f16x4*)(Ch + (size_t)mrow[t] * OUT + o0) = hv;
                }
            }
            if constexpr (FUSES) {
                sp0[t] += acc[0]*w0 + acc[1]*w1 + acc[2]*w2 + acc[3]*w3;
                sp1[t] += acc[0]*u0 + acc[1]*u1 + acc[2]*u2 + acc[3]*u3;
            }
        }
    }
    if constexpr (FUSES) {
#pragma unroll
        for (int t = 0; t < NT; ++t) {
            float p0 = sp0[t], p1 = sp1[t];
            p0 += __shfl_xor(p0, 16); p0 += __shfl_xor(p0, 32);
            p1 += __shfl_xor(p1, 16); p1 += __shfl_xor(p1, 32);
            if (kg == 0 && ok[t])
                *(float2*)(s + 2 * mrow[t]) = make_float2(p0, p1);
        }
    }
}

// ===========================================================================
// CSR scans
// ===========================================================================
#define SCAN_B 256
__global__ __launch_bounds__(SCAN_B) void scan1(const int* __restrict__ cnt,
                                                int* __restrict__ bsum, int Nn)
{
    __shared__ int sm[SCAN_B];
    int i = blockIdx.x * SCAN_B + threadIdx.x;
    sm[threadIdx.x] = (i < Nn) ? cnt[i] : 0;
    __syncthreads();
    for (int off = SCAN_B / 2; off > 0; off >>= 1) {
        if (threadIdx.x < off) sm[threadIdx.x] += sm[threadIdx.x + off];
        __syncthreads();
    }
    if (threadIdx.x == 0) bsum[blockIdx.x] = sm[0];
}

// scan3b: folds the old scan2 (block-prefix of bsum computed per block)
__global__ __launch_bounds__(SCAN_B) void scan3b(const int* __restrict__ cnt,
                                                 const int* __restrict__ bsum,
                                                 int* __restrict__ base,
                                                 int* __restrict__ cursor, int Nn)
{
    __shared__ int sm[SCAN_B];
    __shared__ int spre;
    int acc = 0;
    for (int t = threadIdx.x; t < blockIdx.x; t += SCAN_B) acc += bsum[t];
    sm[threadIdx.x] = acc;
    __syncthreads();
    for (int off = SCAN_B / 2; off > 0; off >>= 1) {
        if (threadIdx.x < off) sm[threadIdx.x] += sm[threadIdx.x + off];
        __syncthreads();
    }
    if (threadIdx.x == 0) spre = sm[0];
    __syncthreads();
    const int bpre = spre;
    __syncthreads();
    int i = blockIdx.x * SCAN_B + threadIdx.x;
    int v = (i < Nn) ? cnt[i] : 0;
    sm[threadIdx.x] = v;
    __syncthreads();
    for (int off = 1; off < SCAN_B; off <<= 1) {
        int u = (threadIdx.x >= off) ? sm[threadIdx.x - off] : 0;
        __syncthreads();
        sm[threadIdx.x] += u;
        __syncthreads();
    }
    if (i < Nn) {
        int b = bpre + sm[threadIdx.x] - v;
        base[i] = b;
        cursor[i] = b;
        if (i == Nn - 1) base[Nn] = b + v;
    }
}

// ---------------------------------------------------------------------------
// XCD-bucketed CSR fill (kills scatter write amplification; see R5 notes)
// ---------------------------------------------------------------------------
__global__ __launch_bounds__(256) void fill_xcd(const int* __restrict__ idx,
                                                int* __restrict__ cursor,
                                                int* __restrict__ adjp,
                                                int E, int Nn)
{
    const int xcd  = blockIdx.x & 7;
    const int gblk = blockIdx.x >> 3;
    const int ngrp = gridDim.x >> 3;
    const int twoE = 2 * E;
    const int lo = xcd * Nn, hi = lo + Nn;
    for (int i = gblk * blockDim.x + threadIdx.x; i < twoE; i += ngrp * blockDim.x) {
        int node = idx[i];
        int n8 = node << 3;
        if (n8 < lo || n8 >= hi) continue;
        int side  = (i >= E);
        int e     = side ? i - E : i;
        int other = side ? idx[e] : idx[E + e];
        int pos = atomicAdd(cursor + node, 1);
        adjp[pos] = other | (side << 31);
    }
}

// ===========================================================================
// per-step fused kernel: FOUR nodes per wave (16-lane groups, 16B/lane).
// h-state lives in f16 (h16); LAST step writes f32 d_out instead.
// ===========================================================================
template<bool LAST>
__global__ __launch_bounds__(256) void agg8(const f16* __restrict__ g16,
                                            const int* __restrict__ adjp,
                                            const int* __restrict__ base,
                                            const float* __restrict__ sIn,
                                            float* __restrict__ sOut,
                                            float* __restrict__ hOut,
                                            f16* __restrict__ h16,
                                            const float* __restrict__ wg,
                                            const float* __restrict__ gbp,
                                            const float* __restrict__ Tp,
                                            float stepf, int Nn, int twoE)
{
    const int lane = threadIdx.x & 63;
    const int grp  = lane >> 4;
    const int gl   = lane & 15;
    const int wvid = (blockIdx.x * blockDim.x + threadIdx.x) >> 6;
    int n = wvid * 4 + grp;
    const bool nOK = (n < Nn);
    if (n >= Nn) n = Nn - 1;
    const float gb = gbp[0];
    const float w  = 1.f / (1.f + expf(-(Tp[0] - stepf)));
    const int b0 = base[n], b1 = base[n + 1];
    const int deg = b1 - b0;
    const float s1n = sIn[2 * n], s2n = sIn[2 * n + 1];
    const int d0 = gl << 3;

    f16x8 o1 = *(const f16x8*)(g16 + (size_t)n * 256 + d0);
    f16x8 o2 = *(const f16x8*)(g16 + (size_t)n * 256 + 128 + d0);
    f16x8 hv16 = *(const f16x8*)(h16 + (size_t)n * DH + d0);

    f16x2 acc0 = {(f16)0.f, (f16)0.f};
    f16x2 acc1 = {(f16)0.f, (f16)0.f};
    f16x2 acc2 = {(f16)0.f, (f16)0.f};
    f16x2 acc3 = {(f16)0.f, (f16)0.f};
    float aPl = 0.f, aCl = 0.f;

    union V8 { f16x8 v; f16x2 h2[4]; };
    union AU { u32 w; f16x2 h; unsigned short us[2]; };

    int t = 0;
    while (__any(t * 16 < deg)) {
        const int done = t * 16;
        int m = deg - done; m = (m < 0) ? 0 : ((m > 16) ? 16 : m);
        int midx = b0 + done + ((gl < m) ? gl : ((m > 0) ? m - 1 : 0));
        midx = (midx < twoE - 1) ? midx : (twoE - 1);
        midx = (midx > 0) ? midx : 0;
        int meta  = adjp[midx];
        int other = meta & 0x7FFFFFFF;
        int side  = ((unsigned)meta) >> 31;
        int eoff  = (other << 8) | ((side ^ 1) << 7);
        float sv  = sIn[2 * other + (side ^ 1)];
        float aE  = 1.f / (1.f + expf(-((side ? s2n : s1n) + sv + gb)));
        if (gl >= m) aE = 0.f;
        aPl += side ? 0.f : aE;
        aCl += side ? aE : 0.f;

        AU apk;
        apk.h[0] = (f16)aE;
        apk.us[1] = apk.us[0];

        const int sb = grp << 4;
        for (int j = 0; j < m; j += 8) {
            V8 gv[8]; u32 ap[8];
#pragma unroll
            for (int u = 0; u < 8; ++u) {
                int es = j + u; es = (es < 15) ? es : 15;
                int eo = __shfl(eoff, sb | es);
                ap[u]  = (u32)__shfl((int)apk.w, sb | es);
                gv[u].v = *(const f16x8*)(g16 + (size_t)(unsigned)eo + d0);
            }
#pragma unroll
            for (int u = 0; u < 8; ++u) {
                AU aa; aa.w = ap[u];
                acc0 += aa.h * gv[u].h2[0];
                acc1 += aa.h * gv[u].h2[1];
                acc2 += aa.h * gv[u].h2[2];
                acc3 += aa.h * gv[u].h2[3];
            }
        }
        ++t;
    }

    float a8[8];
    a8[0] = (float)acc0[0]; a8[1] = (float)acc0[1];
    a8[2] = (float)acc1[0]; a8[3] = (float)acc1[1];
    a8[4] = (float)acc2[0]; a8[5] = (float)acc2[1];
    a8[6] = (float)acc3[0]; a8[7] = (float)acc3[1];

    float aP = aPl, aC = aCl;
#pragma unroll
    for (int off = 8; off > 0; off >>= 1) {
        aP += __shfl_xor(aP, off);
        aC += __shfl_xor(aC, off);
    }
#pragma unroll
    for (int i = 0; i < 8; ++i)
        a8[i] += aP * (float)o1[i] + aC * (float)o2[i];

    float hf[8];
#pragma unroll
    for (int i = 0; i < 8; ++i) {
        hf[i] = (float)hv16[i];
        hf[i] += w * fmaxf(a8[i] + hf[i], 0.f);
    }

    float p0 = 0.f, p1 = 0.f;
    if (nOK) {
        if constexpr (LAST) {
            *(float4*)(hOut + (size_t)n * DH + d0) =
                make_float4(hf[0], hf[1], hf[2], hf[3]);
            *(float4*)(hOut + (size_t)n * DH + d0 + 4) =
                make_float4(hf[4], hf[5], hf[6], hf[7]);
        } else {
            f16x8 h2 = {(f16)hf[0], (f16)hf[1], (f16)hf[2], (f16)hf[3],
                        (f16)hf[4], (f16)hf[5], (f16)hf[6], (f16)hf[7]};
            *(f16x8*)(h16 + (size_t)n * DH + d0) = h2;
        }
    }
    if constexpr (!LAST) {
        float4 w0a = *(const float4*)(wg + d0);
        float4 w0b = *(const float4*)(wg + d0 + 4);
        float4 w1a = *(const float4*)(wg + 128 + d0);
        float4 w1b = *(const float4*)(wg + 128 + d0 + 4);
        p0 = hf[0]*w0a.x + hf[1]*w0a.y + hf[2]*w0a.z + hf[3]*w0a.w
           + hf[4]*w0b.x + hf[5]*w0b.y + hf[6]*w0b.z + hf[7]*w0b.w;
        p1 = hf[0]*w1a.x + hf[1]*w1a.y + hf[2]*w1a.z + hf[3]*w1a.w
           + hf[4]*w1b.x + hf[5]*w1b.y + hf[6]*w1b.z + hf[7]*w1b.w;
#pragma unroll
        for (int off = 8; off > 0; off >>= 1) {
            p0 += __shfl_xor(p0, off);
            p1 += __shfl_xor(p1, off);
        }
        if (gl == 0 && nOK) *(float2*)(sOut + 2 * n) = make_float2(p0, p1);
    }
}

// ---------------------------------------------------------------------------
static inline size_t alignUp(size_t x) { return (x + 255) & ~(size_t)255; }

extern "C" void kernel_launch(void* const* d_in, const int* in_sizes, int n_in,
                              void* d_out, int out_size, void* d_ws, size_t ws_size,
                              hipStream_t stream)
{
    const float* x     = (const float*)d_in[0];
    const int*   idx   = (const int*)d_in[1];
    const float* Ws    = (const float*)d_in[2];
    const float* Wpc   = (const float*)d_in[3];
    const float* Wedge = (const float*)d_in[4];
    const float* Wg    = (const float*)d_in[5];
    const float* Wgb   = (const float*)d_in[6];
    const float* Tp    = (const float*)d_in[7];
    const int Nn = in_sizes[0] / DH;     // 100000
    const int E  = in_sizes[1] / 2;      // 500000
    float* h = (float*)d_out;

    const int nb = (Nn + SCAN_B - 1) / SCAN_B;

    // workspace carve-up
    size_t off = 0;
    char* wsb = (char*)d_ws;
    f16*   g16    = (f16*)  (wsb + off); off = alignUp(off + (size_t)Nn * 256 * 2);
    f16*   h16    = (f16*)  (wsb + off); off = alignUp(off + (size_t)Nn * DH * 2);
    f16*   Ws16   = (f16*)  (wsb + off); off = alignUp(off + 128 * 128 * 2);
    f16*   Bg16   = (f16*)  (wsb + off); off = alignUp(off + 256 * 128 * 2);
    float* sA     = (float*)(wsb + off); off = alignUp(off + (size_t)Nn * 2 * 4);
    float* sB     = (float*)(wsb + off); off = alignUp(off + (size_t)Nn * 2 * 4);
    int*   cnt    = (int*)  (wsb + off); off = alignUp(off + (size_t)Nn * 4);
    int*   base   = (int*)  (wsb + off); off = alignUp(off + (size_t)(Nn + 1) * 4);
    int*   cursor = (int*)  (wsb + off); off = alignUp(off + (size_t)Nn * 4);
    int*   bsum   = (int*)  (wsb + off); off = alignUp(off + (size_t)(nb + 1) * 4);
    int*   adjp   = (int*)  (wsb + off); off = alignUp(off + (size_t)(2 * E + 64) * 4);
    if (off > ws_size) {
        fprintf(stderr, "kernel_launch: ws too small (%zu < %zu)\n", ws_size, off);
        return;
    }

    // ---- CSR build + weights prep ----
    hipMemsetAsync(cnt, 0, (size_t)Nn * 4, stream);
    prep2<<<dim3(2048), dim3(128), 0, stream>>>(Wpc, Wedge, Ws, Bg16, Ws16,
                                                idx, cnt, 2 * E);
    scan1<<<dim3(nb), dim3(SCAN_B), 0, stream>>>(cnt, bsum, Nn);
    scan3b<<<dim3(nb), dim3(SCAN_B), 0, stream>>>(cnt, bsum, base, cursor, Nn);
    fill_xcd<<<dim3(1280), dim3(256), 0, stream>>>(idx, cursor, adjp, E, Nn);

    // ---- init h16 = (x @ Ws^T) as f16 (+ fused s) ----
    mfma_gemm_t<128, 2, true, false, true, true>
        <<<dim3((Nn + 127) / 128), dim3(256), 0, stream>>>(x, Ws16, nullptr, h16,
                                                           Wg, sA, Nn);

    // ---- 3 steps ----
    const int aggBlocks = (Nn * 16 + 255) / 256;
    float* sCur = sA; float* sNxt = sB;
    for (int step = 0; step < 3; ++step) {
        mfma_gemm_t<256, 4, false, false, true, false>
            <<<dim3((Nn + 255) / 256), dim3(256), 0, stream>>>(h16, Bg16, nullptr, g16,
                                                               nullptr, nullptr, Nn);
        if (step < 2)
            agg8<false><<<dim3(aggBlocks), dim3(256), 0, stream>>>(g16, adjp, base, sCur,
                                                                   sNxt, h, h16, Wg, Wgb,
                                                                   Tp, (float)step, Nn, 2 * E);
        else
            agg8<true><<<dim3(aggBlocks), dim3(256), 0, stream>>>(g16, adjp, base, sCur,
                                                                  sNxt, h, h16, Wg, Wgb,
                                                                  Tp, (float)step, Nn, 2 * E);
        float* t = sCur; sCur = sNxt; sNxt = t;
    }
}